// Round 2
// baseline (410.571 us; speedup 1.0000x reference)
//
#include <hip/hip_runtime.h>
#include <cstdint>
#include <cstring>
#include <cmath>

#define PI_F 3.14159265358979323846f

// ---------------------------------------------------------------------------
// Host-side exact reproduction of np.random.RandomState(seed).standard_normal
// (MT19937 + legacy Marsaglia polar gauss), computed once at library load.
// ---------------------------------------------------------------------------
namespace {

struct MT19937 {
  uint32_t mt[624];
  int mti;
  bool has_g;
  double gval;
  void seed(uint32_t s) {
    for (int pos = 0; pos < 624; pos++) {
      mt[pos] = s;
      s = 1812433253u * (s ^ (s >> 30)) + (uint32_t)pos + 1u;
    }
    mti = 624;
    has_g = false;
    gval = 0.0;
  }
  uint32_t next() {
    if (mti >= 624) {
      for (int i = 0; i < 624; i++) {
        uint32_t y = (mt[i] & 0x80000000u) | (mt[(i + 1) % 624] & 0x7fffffffu);
        mt[i] = mt[(i + 397) % 624] ^ (y >> 1) ^ ((y & 1u) ? 0x9908b0dfu : 0u);
      }
      mti = 0;
    }
    uint32_t y = mt[mti++];
    y ^= y >> 11;
    y ^= (y << 7) & 0x9d2c5680u;
    y ^= (y << 15) & 0xefc60000u;
    y ^= y >> 18;
    return y;
  }
  double rdouble() {
    uint32_t a = next() >> 5, b = next() >> 6;
    return ((double)a * 67108864.0 + (double)b) / 9007199254740992.0;
  }
  double gauss() {
    if (has_g) { has_g = false; return gval; }
    double f, x1, x2, r2;
    do {
      x1 = 2.0 * rdouble() - 1.0;
      x2 = 2.0 * rdouble() - 1.0;
      r2 = x1 * x1 + x2 * x2;
    } while (r2 >= 1.0 || r2 == 0.0);
    f = sqrt(-2.0 * log(r2) / r2);
    gval = f * x1;
    has_g = true;
    return f * x2;
  }
};

// table enumeration order; offsets must match cg_off() below
static const int kTbl[14][3] = {
    {0,0,0},{1,0,1},{1,1,0},{1,1,1},{1,1,2},{2,0,2},{2,1,1},
    {2,1,2},{2,1,3},{2,2,0},{2,2,1},{2,2,2},{2,2,3},{2,2,4}};

float g_cg_host[966];

struct CGInit {
  CGInit() {
    MT19937 rs;
    int off = 0;
    for (int t = 0; t < 14; t++) {
      int l1 = kTbl[t][0], l2 = kTbl[t][1], l3 = kTbl[t][2];
      rs.seed((uint32_t)(1000 + l1 * 100 + l2 * 10 + l3));
      int sz = (2 * l1 + 1) * (2 * l2 + 1) * (2 * l3 + 1);
      for (int k = 0; k < sz; k++) g_cg_host[off + k] = (float)rs.gauss();
      off += sz;
    }
  }
} g_cg_init;

}  // namespace

// ---------------------------------------------------------------------------
// Device kernel
// ---------------------------------------------------------------------------

__host__ __device__ constexpr int cg_off(int l1, int l2, int l3) {
  // offsets of each (l1,l2,l3) table in the 966-float cg buffer
  return (l1 == 0) ? 0
       : (l1 == 1) ? ((l2 == 0) ? 1 : (l3 == 0 ? 10 : (l3 == 1 ? 19 : 46)))
       : (l2 == 0) ? 91
       : (l2 == 1) ? (l3 == 1 ? 116 : (l3 == 2 ? 161 : 236))
                   : (l3 == 0 ? 341 : (l3 == 1 ? 366 : (l3 == 2 ? 441 : (l3 == 3 ? 566 : 741))));
}

template <int L1, int L2>
__device__ __forceinline__ void block_cd(const float (&co)[25], float* __restrict__ sb,
                                         const float* __restrict__ s_cg,
                                         const float* __restrict__ s_coll, int lane,
                                         float* __restrict__ outp) {
  constexpr int M = 2 * L1 + 1, N = 2 * L2 + 1;
  constexpr int Ar = (L1 == 0) ? 3 : ((L1 == 1) ? 2 : 1);
  constexpr int Br = (L2 == 0) ? 3 : ((L2 == 1) ? 2 : 1);

  // Phase C: Mx[m,n] (this lane's feature f) = sum_{l3,a} cg[m,n,a] * c_out[l3][f,a]
  float mx[M * N];
#pragma unroll
  for (int x = 0; x < M * N; x++) mx[x] = 0.f;
#pragma unroll
  for (int l3 = L1 - L2; l3 <= L1 + L2; l3++) {
    const float* cg = s_cg + cg_off(L1, L2, l3);
    const int K3 = 2 * l3 + 1;
#pragma unroll
    for (int m = 0; m < M; m++)
#pragma unroll
      for (int n = 0; n < N; n++)
#pragma unroll
        for (int a = 0; a < 2 * l3 + 1; a++)
          mx[m * N + n] += cg[(m * N + n) * K3 + a] * co[l3 * l3 + a];
  }
  // stash to LDS, stride 17 (coprime with 32 banks -> conflict-free transposed reads)
#pragma unroll
  for (int x = 0; x < M * N; x++) sb[x * 17 + lane] = mx[x];
  __syncthreads();

  // Phase D: collapse over f and write output (plus transpose for off-diag blocks)
  constexpr int E = M * N * Ar * Br;
  constexpr int colDim = N * Br;
  constexpr int ab = (L1 == 0) ? 0 : ((L1 == 1) ? 3 : 5);
  constexpr int bb = (L2 == 0) ? 0 : ((L2 == 1) ? 3 : 5);
  constexpr int rb1 = (L1 == 0) ? 0 : ((L1 == 1) ? 3 : 9);
  constexpr int rb2 = (L2 == 0) ? 0 : ((L2 == 1) ? 3 : 9);
  for (int e = lane; e < E; e += 16) {
    int b = e % Br;
    int t = e / Br;
    int a = t % Ar;
    t /= Ar;
    int n = t % N;
    int m = t / N;
    int mn = m * N + n;
    float acc = 0.f;
#pragma unroll
    for (int f = 0; f < 16; f++)
      acc += sb[mn * 17 + f] * s_coll[(ab + a) * 16 + f] * s_coll[(bb + b) * 16 + f];
    int ri = e / colDim, ci = e % colDim;  // raw-reshape semantics of (M,N,Ar,Br)->(M*Ar, N*Br)
    outp[(rb1 + ri) * 14 + (rb2 + ci)] = acc;
    if (L1 != L2) outp[(rb2 + ci) * 14 + (rb1 + ri)] = acc;
  }
  __syncthreads();
}

__global__ __launch_bounds__(256) void outlayer_kernel(
    const float* __restrict__ c0, const float* __restrict__ c1,
    const float* __restrict__ c2, const float* __restrict__ c3,
    const float* __restrict__ c4, const float* __restrict__ R,
    const float* __restrict__ w_rad, const float* __restrict__ weight,
    const float* __restrict__ s_col, const float* __restrict__ p_col,
    const float* __restrict__ d_col, const int* __restrict__ Z,
    const int* __restrict__ api, const int* __restrict__ aidx,
    const float* __restrict__ cg_g, float* __restrict__ out) {
  __shared__ float s_wrad[2560];     // (L,K,F) fp32
  __shared__ float s_coll[96];       // s(3),p(2),d(1) rows x16
  __shared__ float s_cg[966];
  __shared__ float s_buf[16 * 440];  // per-pair scratch: h (400) then Mx (<=25*17)

  const int tid = threadIdx.x;

  // stage shared constants
#pragma unroll
  for (int t = 0; t < 10; t++)
    s_wrad[tid + t * 256] = w_rad[tid + t * 256];
  if (tid < 96) {
    float v;
    if (tid < 48) v = s_col[tid];
    else if (tid < 80) v = p_col[tid - 48];
    else v = d_col[tid - 80];
    s_coll[tid] = v;
  }
  for (int e = tid; e < 966; e += 256) s_cg[e] = cg_g[e];
  __syncthreads();

  const int grp = tid >> 4;
  const int lane = tid & 15;  // feature index f
  const int p = blockIdx.x * 16 + grp;  // P=50000 = 3125*16 exactly
  float* sb = s_buf + grp * 440;

  const int i = api[2 * p], j = api[2 * p + 1];
  const int ai = aidx[p];
  const int t1 = Z[api[2 * ai]], t2 = Z[api[2 * ai + 1]];

  // radial part (redundant across the 16 lanes of a group; broadcast loads)
  float dx = R[3 * i + 0] - R[3 * j + 0];
  float dy = R[3 * i + 1] - R[3 * j + 1];
  float dz = R[3 * i + 2] - R[3 * j + 2];
  float d = sqrtf(dx * dx + dy * dy + dz * dz);
  float env = 0.0f;
  if (d < 5.0f) env = 0.5f * (cosf(PI_F * d * 0.2f) + 1.0f);
  float th = PI_F * d * 0.2f;
  float rlo = sinf((float)(lane + 1) * th) * env;   // rbf[lane]
  float rhi = sinf((float)(lane + 17) * th) * env;  // rbf[lane+16]

  // g[l][f] = sum_k rbf[k] * w_rad[l,k,f]
  float gl[5] = {0.f, 0.f, 0.f, 0.f, 0.f};
#pragma unroll
  for (int k = 0; k < 16; k++) {
    float rv = __shfl(rlo, k, 16);
#pragma unroll
    for (int l = 0; l < 5; l++) gl[l] += rv * s_wrad[l * 512 + k * 16 + lane];
  }
#pragma unroll
  for (int k = 0; k < 16; k++) {
    float rv = __shfl(rhi, k, 16);
#pragma unroll
    for (int l = 0; l < 5; l++) gl[l] += rv * s_wrad[l * 512 + (k + 16) * 16 + lane];
  }

  // Phase A: h[l][f][m] = g[l][f]*(c[l][i,f,m]+c[l][j,f,m])  -> LDS [l: m*16+f]
  const float* cl[5] = {c0, c1, c2, c3, c4};
#pragma unroll
  for (int l = 0; l < 5; l++) {
    const int nm = 2 * l + 1;
    const float* ci = cl[l] + (size_t)(i * 16 + lane) * nm;
    const float* cj = cl[l] + (size_t)(j * 16 + lane) * nm;
#pragma unroll
    for (int m = 0; m < 2 * l + 1; m++) {
      sb[16 * l * l + m * 16 + lane] = gl[l] * (ci[m] + cj[m]);
    }
  }
  __syncthreads();

  // Phase B: c_out[l][b=lane][m] = sum_c gw[l][b][c] * h[l][c][m]
  float co[25];
#pragma unroll
  for (int x = 0; x < 25; x++) co[x] = 0.f;
  const float* w1 = weight + (size_t)(t1 * 10 + t2) * 1280;
  const float* w2 = weight + (size_t)(t2 * 10 + t1) * 1280;
#pragma unroll
  for (int l = 0; l < 5; l++) {
    // 16 consecutive floats per lane: vectorize as 4x float4
#pragma unroll
    for (int cq = 0; cq < 4; cq++) {
      const float4 a4 = *(const float4*)(w1 + l * 256 + lane * 16 + cq * 4);
      const float4 b4 = *(const float4*)(w2 + l * 256 + lane * 16 + cq * 4);
      float gw[4] = {a4.x + b4.x, a4.y + b4.y, a4.z + b4.z, a4.w + b4.w};
#pragma unroll
      for (int cc = 0; cc < 4; cc++) {
        const int c = cq * 4 + cc;
#pragma unroll
        for (int m = 0; m < 2 * l + 1; m++)
          co[l * l + m] += gw[cc] * sb[16 * l * l + m * 16 + c];
      }
    }
  }
  __syncthreads();  // before sb is reused for Mx

  // Phases C+D per output block
  float* outp = out + (size_t)p * 196;
  block_cd<0, 0>(co, sb, s_cg, s_coll, lane, outp);
  block_cd<1, 0>(co, sb, s_cg, s_coll, lane, outp);
  block_cd<1, 1>(co, sb, s_cg, s_coll, lane, outp);
  block_cd<2, 0>(co, sb, s_cg, s_coll, lane, outp);
  block_cd<2, 1>(co, sb, s_cg, s_coll, lane, outp);
  block_cd<2, 2>(co, sb, s_cg, s_coll, lane, outp);
}

// ---------------------------------------------------------------------------
// Launch
// ---------------------------------------------------------------------------
extern "C" void kernel_launch(void* const* d_in, const int* in_sizes, int n_in,
                              void* d_out, int out_size, void* d_ws, size_t ws_size,
                              hipStream_t stream) {
  (void)in_sizes; (void)n_in; (void)out_size; (void)ws_size;

  // one-time pinned staging of the cg table (host alloc only on first,
  // uncaptured call; the captured GPU work is identical every call)
  static float* s_pinned = nullptr;
  if (!s_pinned) {
    float* pp = nullptr;
    if (hipHostMalloc((void**)&pp, sizeof(g_cg_host), hipHostMallocDefault) == hipSuccess && pp) {
      memcpy(pp, g_cg_host, sizeof(g_cg_host));
      s_pinned = pp;
    } else {
      s_pinned = g_cg_host;  // pageable fallback
    }
  }
  hipMemcpyAsync(d_ws, s_pinned, sizeof(g_cg_host), hipMemcpyHostToDevice, stream);

  const float* c0 = (const float*)d_in[0];
  const float* c1 = (const float*)d_in[1];
  const float* c2 = (const float*)d_in[2];
  const float* c3 = (const float*)d_in[3];
  const float* c4 = (const float*)d_in[4];
  const float* R = (const float*)d_in[5];
  const float* w_rad = (const float*)d_in[6];
  const float* weight = (const float*)d_in[7];
  const float* s_col = (const float*)d_in[8];
  const float* p_col = (const float*)d_in[9];
  const float* d_col = (const float*)d_in[10];
  const int* Z = (const int*)d_in[11];
  const int* api = (const int*)d_in[12];
  const int* aidx = (const int*)d_in[13];

  dim3 grid(3125), block(256);  // 50000 pairs, 16 pairs/block
  hipLaunchKernelGGL(outlayer_kernel, grid, block, 0, stream,
                     c0, c1, c2, c3, c4, R, w_rad, weight, s_col, p_col, d_col,
                     Z, api, aidx, (const float*)d_ws, (float*)d_out);
}

// Round 3
// 207.462 us; speedup vs baseline: 1.9790x; 1.9790x over previous
//
#include <hip/hip_runtime.h>
#include <cstdint>
#include <cstring>
#include <cmath>

#define PI_F 3.14159265358979323846f

// ---------------------------------------------------------------------------
// Host-side exact reproduction of np.random.RandomState(seed).standard_normal
// (MT19937 + legacy Marsaglia polar gauss) + packing of CG/index tables.
// ---------------------------------------------------------------------------
namespace {

struct MT19937 {
  uint32_t mt[624];
  int mti;
  bool has_g;
  double gval;
  void seed(uint32_t s) {
    for (int pos = 0; pos < 624; pos++) {
      mt[pos] = s;
      s = 1812433253u * (s ^ (s >> 30)) + (uint32_t)pos + 1u;
    }
    mti = 624;
    has_g = false;
    gval = 0.0;
  }
  uint32_t next() {
    if (mti >= 624) {
      for (int i = 0; i < 624; i++) {
        uint32_t y = (mt[i] & 0x80000000u) | (mt[(i + 1) % 624] & 0x7fffffffu);
        mt[i] = mt[(i + 397) % 624] ^ (y >> 1) ^ ((y & 1u) ? 0x9908b0dfu : 0u);
      }
      mti = 0;
    }
    uint32_t y = mt[mti++];
    y ^= y >> 11;
    y ^= (y << 7) & 0x9d2c5680u;
    y ^= (y << 15) & 0xefc60000u;
    y ^= y >> 18;
    return y;
  }
  double rdouble() {
    uint32_t a = next() >> 5, b = next() >> 6;
    return ((double)a * 67108864.0 + (double)b) / 9007199254740992.0;
  }
  double gauss() {
    if (has_g) { has_g = false; return gval; }
    double f, x1, x2, r2;
    do {
      x1 = 2.0 * rdouble() - 1.0;
      x2 = 2.0 * rdouble() - 1.0;
      r2 = x1 * x1 + x2 * x2;
    } while (r2 >= 1.0 || r2 == 0.0);
    f = sqrt(-2.0 * log(r2) / r2);
    gval = f * x1;
    has_g = true;
    return f * x2;
  }
};

constexpr int cg_off(int l1, int l2, int l3) {
  return (l1 == 0) ? 0
       : (l1 == 1) ? ((l2 == 0) ? 1 : (l3 == 0 ? 10 : (l3 == 1 ? 19 : 46)))
       : (l2 == 0) ? 91
       : (l2 == 1) ? (l3 == 1 ? 116 : (l3 == 2 ? 161 : 236))
                   : (l3 == 0 ? 341 : (l3 == 1 ? 366 : (l3 == 2 ? 441 : (l3 == 3 ? 566 : 741))));
}

static const int kTbl[14][3] = {
    {0,0,0},{1,0,1},{1,1,0},{1,1,1},{1,1,2},{2,0,2},{2,1,1},
    {2,1,2},{2,1,3},{2,2,0},{2,2,1},{2,2,2},{2,2,3},{2,2,4}};

float g_cg_host[966];

// Staging buffer pushed to d_ws every launch:
//   [0,966)      cgR   : per-block CG matrices, row mn, cols = concat x-range
//   [966,1099)   tabC  : u | v<<4 | x<<8        (133 ints, Dtab order)
//   [1100,1632)  tabD  : int4 per output element (133), sorted by row length
uint32_t g_stage[1632];

static const int kBk[6][2] = {{0,0},{1,0},{1,1},{2,0},{2,1},{2,2}};

struct CGInit {
  CGInit() {
    MT19937 rs;
    {
      int off = 0;
      for (int t = 0; t < 14; t++) {
        int l1 = kTbl[t][0], l2 = kTbl[t][1], l3 = kTbl[t][2];
        rs.seed((uint32_t)(1000 + l1 * 100 + l2 * 10 + l3));
        int sz = (2 * l1 + 1) * (2 * l2 + 1) * (2 * l3 + 1);
        for (int k = 0; k < sz; k++) g_cg_host[off + k] = (float)rs.gauss();
        off += sz;
      }
    }
    int cgbase[6], dbase[6], xlenA[6];
    int xsAll[6][25];
    int off = 0, doff = 0;
    for (int bk = 0; bk < 6; bk++) {
      int l1 = kBk[bk][0], l2 = kBk[bk][1];
      int M = 2 * l1 + 1, N = 2 * l2 + 1;
      int Ar = (l1 == 0) ? 3 : (l1 == 1) ? 2 : 1;
      int Br = (l2 == 0) ? 3 : (l2 == 1) ? 2 : 1;
      int xs[25], xl3[25], xa[25], cnt = 0;
      for (int l3 = l1 - l2; l3 <= l1 + l2; l3++)
        for (int a = 0; a < 2 * l3 + 1; a++) {
          xs[cnt] = l3 * l3 + a; xl3[cnt] = l3; xa[cnt] = a; cnt++;
        }
      int xlen = cnt;
      xlenA[bk] = xlen; cgbase[bk] = off; dbase[bk] = doff;
      for (int x = 0; x < xlen; x++) xsAll[bk][x] = xs[x];
      // CG matrix
      for (int mn = 0; mn < M * N; mn++)
        for (int xi = 0; xi < xlen; xi++) {
          int l3 = xl3[xi], K3 = 2 * l3 + 1;
          float v = g_cg_host[cg_off(l1, l2, l3) + mn * K3 + xa[xi]];
          memcpy(&g_stage[off + mn * xlen + xi], &v, 4);
        }
      off += M * N * xlen;
      // tabC
      for (int a = 0; a < Ar; a++)
        for (int b = 0; b < Br; b++) {
          int q = a * Br + b;
          int u = (l1 == 0) ? a : (l1 == 1) ? 3 + a : 5;
          int v = (l2 == 0) ? b : (l2 == 1) ? 3 + b : 5;
          for (int xi = 0; xi < xlen; xi++)
            g_stage[966 + doff + q * xlen + xi] =
                (uint32_t)(u | (v << 4) | (xs[xi] << 8));
        }
      doff += Ar * Br * xlen;
    }
    // tabD, blocks sorted by descending row length for strip balance
    static const int ord[6] = {5, 4, 2, 3, 1, 0};
    int ei = 0;
    for (int bo = 0; bo < 6; bo++) {
      int bk = ord[bo];
      int l1 = kBk[bk][0], l2 = kBk[bk][1];
      int M = 2 * l1 + 1, N = 2 * l2 + 1;
      int Ar = (l1 == 0) ? 3 : (l1 == 1) ? 2 : 1;
      int Br = (l2 == 0) ? 3 : (l2 == 1) ? 2 : 1;
      int rb1 = (l1 == 0) ? 0 : (l1 == 1) ? 3 : 9;
      int rb2 = (l2 == 0) ? 0 : (l2 == 1) ? 3 : 9;
      int colDim = N * Br, xlen = xlenA[bk];
      for (int e = 0; e < M * N * Ar * Br; e++) {
        int b = e % Br, t = e / Br;
        int a = t % Ar; t /= Ar;
        int n = t % N, m = t / N;
        int mn = m * N + n, q = a * Br + b;
        int ri = e / colDim, ci = e % colDim;
        int p1 = (rb1 + ri) * 14 + (rb2 + ci);
        int p2 = (l1 == l2) ? p1 : ((rb2 + ci) * 14 + (rb1 + ri));
        uint32_t* w = &g_stage[1100 + 4 * ei];
        w[0] = (uint32_t)((cgbase[bk] + mn * xlen) | (xlen << 16));
        w[1] = (uint32_t)(dbase[bk] + q * xlen);
        w[2] = (uint32_t)p1;
        w[3] = (uint32_t)p2;
        ei++;
      }
    }
  }
} g_cg_init;

}  // namespace

// ---------------------------------------------------------------------------
// Device kernel: 16 lanes per pair (lane = feature), 16 pairs per 256-block.
// Per-pair LDS: regionA[400] = h -> (reused) out_stage; co[lane*25+x] also in
// regionA; regionB[136] = Dtab.  6 barriers total.
// ---------------------------------------------------------------------------
#define PSTRIDE 536  // 400 regionA + 136 regionB; 536%32==24 -> group bank spread

__global__ __launch_bounds__(256, 4) void outlayer_kernel(
    const float* __restrict__ c0, const float* __restrict__ c1,
    const float* __restrict__ c2, const float* __restrict__ c3,
    const float* __restrict__ c4, const float* __restrict__ R,
    const float* __restrict__ w_rad, const float* __restrict__ weight,
    const float* __restrict__ s_colg, const float* __restrict__ p_colg,
    const float* __restrict__ d_colg, const int* __restrict__ Z,
    const int* __restrict__ api, const int* __restrict__ aidx,
    const float* __restrict__ cgR, const int* __restrict__ tabC,
    const int* __restrict__ tabD, float* __restrict__ out) {
  __shared__ float s_wrad[2560];
  __shared__ float s_cg[966];
  __shared__ float s_w6[36 * 17];  // coll_u*coll_v products, stride-17 pad
  __shared__ float s_buf[16 * PSTRIDE];

  const int tid = threadIdx.x;

#pragma unroll
  for (int t = 0; t < 10; t++) s_wrad[tid + t * 256] = w_rad[tid + t * 256];
  for (int e = tid; e < 966; e += 256) s_cg[e] = cgR[e];
  for (int idx = tid; idx < 576; idx += 256) {
    int comb = idx >> 4, f = idx & 15;
    int u = comb / 6, v = comb % 6;
    float cu = (u < 3) ? s_colg[u * 16 + f] : (u < 5) ? p_colg[(u - 3) * 16 + f] : d_colg[f];
    float cv = (v < 3) ? s_colg[v * 16 + f] : (v < 5) ? p_colg[(v - 3) * 16 + f] : d_colg[f];
    s_w6[comb * 17 + f] = cu * cv;
  }
  __syncthreads();

  const int grp = tid >> 4;
  const int lane = tid & 15;
  const int p = blockIdx.x * 16 + grp;  // P = 50000 = 3125*16 exactly
  float* sb = s_buf + grp * PSTRIDE;
  float* sbD = sb + 400;

  const int i = api[2 * p], j = api[2 * p + 1];
  const int ai = aidx[p];
  const int t1 = Z[api[2 * ai]], t2 = Z[api[2 * ai + 1]];

  // --- radial basis ---
  float dx = R[3 * i + 0] - R[3 * j + 0];
  float dy = R[3 * i + 1] - R[3 * j + 1];
  float dz = R[3 * i + 2] - R[3 * j + 2];
  float d = sqrtf(dx * dx + dy * dy + dz * dz);
  float env = 0.0f;
  if (d < 5.0f) env = 0.5f * (cosf(PI_F * d * 0.2f) + 1.0f);
  float th = PI_F * d * 0.2f;
  float rlo = sinf((float)(lane + 1) * th) * env;
  float rhi = sinf((float)(lane + 17) * th) * env;

  // g[l][f=lane]
  float gl[5] = {0.f, 0.f, 0.f, 0.f, 0.f};
#pragma unroll
  for (int k = 0; k < 16; k++) {
    float rv = __shfl(rlo, k, 16);
#pragma unroll
    for (int l = 0; l < 5; l++) gl[l] += rv * s_wrad[l * 512 + k * 16 + lane];
  }
#pragma unroll
  for (int k = 0; k < 16; k++) {
    float rv = __shfl(rhi, k, 16);
#pragma unroll
    for (int l = 0; l < 5; l++) gl[l] += rv * s_wrad[l * 512 + (k + 16) * 16 + lane];
  }

  // --- Phase A: h[l][m][c] = g[l][c]*(c_l[i,c,m]+c_l[j,c,m]) -> regionA, coalesced reads
  const float* cl[5] = {c0, c1, c2, c3, c4};
#pragma unroll
  for (int l = 0; l < 5; l++) {
    const int nm = 2 * l + 1;
    const float* ci = cl[l] + (size_t)i * 16 * nm;
    const float* cj = cl[l] + (size_t)j * 16 * nm;
#pragma unroll
    for (int t = 0; t < 2 * l + 1; t++) {
      int flat = t * 16 + lane;          // coalesced over lanes
      int f = flat / nm, m = flat - f * nm;
      float gf = __shfl(gl[l], f, 16);
      sb[16 * l * l + m * 16 + f] = gf * (ci[flat] + cj[flat]);
    }
  }
  __syncthreads();

  // --- Phase B: co[x=l^2+m] = sum_c gw[lane][c] * h[l][m][c]
  float co[25];
#pragma unroll
  for (int x = 0; x < 25; x++) co[x] = 0.f;
  const float* w1 = weight + (size_t)(t1 * 10 + t2) * 1280 + lane * 16;
  const float* w2 = weight + (size_t)(t2 * 10 + t1) * 1280 + lane * 16;
#pragma unroll
  for (int l = 0; l < 5; l++) {
    float gwreg[16];
#pragma unroll
    for (int cq = 0; cq < 4; cq++) {
      float4 a4 = *(const float4*)(w1 + l * 256 + cq * 4);
      float4 b4 = *(const float4*)(w2 + l * 256 + cq * 4);
      gwreg[cq * 4 + 0] = a4.x + b4.x;
      gwreg[cq * 4 + 1] = a4.y + b4.y;
      gwreg[cq * 4 + 2] = a4.z + b4.z;
      gwreg[cq * 4 + 3] = a4.w + b4.w;
    }
#pragma unroll
    for (int m = 0; m < 2 * l + 1; m++) {
      const float* hb = &sb[16 * l * l + m * 16];
      float acc = co[l * l + m];
#pragma unroll
      for (int cq = 0; cq < 4; cq++) {
        float4 h4 = *(const float4*)(hb + cq * 4);  // broadcast within group
        acc += gwreg[cq * 4 + 0] * h4.x + gwreg[cq * 4 + 1] * h4.y +
               gwreg[cq * 4 + 2] * h4.z + gwreg[cq * 4 + 3] * h4.w;
      }
      co[l * l + m] = acc;
    }
  }
  __syncthreads();  // WAR: co overwrite of h region

  // co -> LDS [f*25 + x]
#pragma unroll
  for (int x = 0; x < 25; x++) sb[lane * 25 + x] = co[x];
  __syncthreads();

  // --- Phase C': Dtab[t] = sum_f w_uv[f] * co[f][x]
#pragma unroll
  for (int it = 0; it < 9; it++) {
    int t = it * 16 + lane;
    if (t < 133) {
      int pc = tabC[t];
      int u = pc & 15, v = (pc >> 4) & 15, x = pc >> 8;
      const float* wrow = &s_w6[(u * 6 + v) * 17];
      float acc = 0.f;
#pragma unroll
      for (int f = 0; f < 16; f++) acc += wrow[f] * sb[f * 25 + x];
      sbD[t] = acc;
    }
  }
  __syncthreads();

  // --- Phase D': out element = CG row . Dtab slice -> out_stage (regionA)
#pragma unroll
  for (int it = 0; it < 9; it++) {
    int t = it * 16 + lane;
    if (t < 133) {
      int4 td = *(const int4*)(tabD + 4 * t);
      int goff = td.x & 0xffff, len = td.x >> 16, doff = td.y;
      float acc = 0.f;
      for (int xi = 0; xi < len; xi++) acc += s_cg[goff + xi] * sbD[doff + xi];
      sb[td.z] = acc;
      sb[td.w] = acc;  // transpose copy (== td.z for diagonal blocks)
    }
  }
  __syncthreads();

  // --- coalesced float4 writeout of the staged 196 floats
  float* outp = out + (size_t)p * 196;
#pragma unroll
  for (int r = 0; r < 4; r++) {
    int idx = r * 16 + lane;
    if (idx < 49) {
      float4 v = *(const float4*)&sb[idx * 4];
      *(float4*)(outp + idx * 4) = v;
    }
  }
}

// ---------------------------------------------------------------------------
// Launch
// ---------------------------------------------------------------------------
extern "C" void kernel_launch(void* const* d_in, const int* in_sizes, int n_in,
                              void* d_out, int out_size, void* d_ws, size_t ws_size,
                              hipStream_t stream) {
  (void)in_sizes; (void)n_in; (void)out_size; (void)ws_size;

  static uint32_t* s_pinned = nullptr;
  if (!s_pinned) {
    uint32_t* pp = nullptr;
    if (hipHostMalloc((void**)&pp, sizeof(g_stage), hipHostMallocDefault) == hipSuccess && pp) {
      memcpy(pp, g_stage, sizeof(g_stage));
      s_pinned = pp;
    } else {
      s_pinned = g_stage;
    }
  }
  hipMemcpyAsync(d_ws, s_pinned, sizeof(g_stage), hipMemcpyHostToDevice, stream);

  const float* c0 = (const float*)d_in[0];
  const float* c1 = (const float*)d_in[1];
  const float* c2 = (const float*)d_in[2];
  const float* c3 = (const float*)d_in[3];
  const float* c4 = (const float*)d_in[4];
  const float* R = (const float*)d_in[5];
  const float* w_rad = (const float*)d_in[6];
  const float* weight = (const float*)d_in[7];
  const float* s_col = (const float*)d_in[8];
  const float* p_col = (const float*)d_in[9];
  const float* d_col = (const float*)d_in[10];
  const int* Z = (const int*)d_in[11];
  const int* api = (const int*)d_in[12];
  const int* aidx = (const int*)d_in[13];

  const float* cgR = (const float*)d_ws;
  const int* tabC = (const int*)d_ws + 966;
  const int* tabD = (const int*)d_ws + 1100;

  dim3 grid(3125), block(256);
  hipLaunchKernelGGL(outlayer_kernel, grid, block, 0, stream,
                     c0, c1, c2, c3, c4, R, w_rad, weight, s_col, p_col, d_col,
                     Z, api, aidx, cgR, tabC, tabD, (float*)d_out);
}